// Round 6
// baseline (363.444 us; speedup 1.0000x reference)
//
#include <hip/hip_runtime.h>
#include <hip/hip_bf16.h>

#define NB 64
#define NP 8732
#define NO 32
#define NC 81
#define NROWS (NB * NP)          // 558848 = 2183*256
#define PBLK 2183

// ws layout: [0,16384)      u64 bestPrior[NB*NO] packed (iou_bits<<32)|~p
//            [16384,16400)  float accum[4] {cross, l1, iou, npos}
//            [16400,16404)  int flag (1 = f32 inputs, 0 = bf16)
// HISTORY: inputs are FLOAT32 at runtime (flag=1 is the passing path); the
// runtime-dtype flag is load-bearing — do not hard-code a dtype.
// R9: prep+ce fused (block owns 256 rows; labels via LDS); lab8 buffer gone.
// R10: DPP row_ror reductions; 4 row-streams. Measured: 149->144.5 only;
//      VGPR=28 -> compiler sank loads, streams serialized; latency-bound.
// R13: explicit 2-deep pipeline (ping-pong vA/vB + sched_barrier(0)) worked
//      (VGPR 52) BUT __launch_bounds__(256,2) CAPPED occupancy at 2
//      waves/SIMD (29.5%) -> ILP gain cancelled by TLP loss; 138 us.
// R14: same pipeline, launch_bounds(256) only — restore TLP on top of ILP.
//      DO NOT re-add a second launch_bounds arg: it caps waves/EU on hipcc.

__device__ __forceinline__ float ldT(const float* p, size_t i) { return p[i]; }
__device__ __forceinline__ float ldT(const unsigned short* p, size_t i) {
    return __uint_as_float((unsigned)p[i] << 16);
}
__device__ __forceinline__ float4 ld4(const float* p, size_t i) {
    return *(const float4*)(p + i);
}
__device__ __forceinline__ float4 ld4(const unsigned short* p, size_t i) {
    ushort4 u = *(const ushort4*)(p + i);
    return make_float4(__uint_as_float((unsigned)u.x << 16),
                       __uint_as_float((unsigned)u.y << 16),
                       __uint_as_float((unsigned)u.z << 16),
                       __uint_as_float((unsigned)u.w << 16));
}

// DPP row_ror:N within each 16-lane row — VALU-pipe cross-lane, no LDS.
template <int CTRL>
__device__ __forceinline__ float dppf(float x) {
    return __int_as_float(__builtin_amdgcn_update_dpp(
        0, __float_as_int(x), CTRL, 0xF, 0xF, true));
}
// full 16-lane reduce: ror 8,4,2,1 (all lanes end with the total)
#define DPP_RED16(var, OP)                      \
    var = OP(var, dppf<0x128>(var));            \
    var = OP(var, dppf<0x124>(var));            \
    var = OP(var, dppf<0x122>(var));            \
    var = OP(var, dppf<0x121>(var));
__device__ __forceinline__ float addf(float a, float b) { return a + b; }

__global__ void init_kernel(const void* __restrict__ prior,
                            unsigned long long* __restrict__ bestPrior,
                            float* __restrict__ accum, int* __restrict__ flag) {
    int i = threadIdx.x;
    for (int j = i; j < NB * NO; j += blockDim.x) bestPrior[j] = 0ull;
    if (i < 4) accum[i] = 0.0f;
    if (i < 64) {
        const unsigned short* pb = (const unsigned short*)prior;
        float v = __uint_as_float((unsigned)pb[i] << 16);
        unsigned long long bad = __ballot(!(fabsf(v) <= 8.0f));
        if (i == 0) *flag = (__popcll(bad) >= 8) ? 1 : 0;
    }
}

// Per-(b,o) argmax over priors (R7/R8-proven): strict > keeps first max;
// packed u64 atomicMax merges (larger iou wins; ties -> smaller p via ~p).
template <typename T>
__device__ __forceinline__ void match_body(
        const T* __restrict__ prior, const T* __restrict__ tb,
        unsigned long long* __restrict__ bestPrior) {
    const int b   = blockIdx.y;
    const int o   = threadIdx.x & 31;
    const int seg = threadIdx.x >> 5;
    const int p0  = blockIdx.x * 256 + seg * 32;

    float4 t = ld4(tb, ((size_t)(b * NO + o)) * 4);
    float tx0 = t.x, ty0 = t.y, tx1 = t.x + t.z, ty1 = t.y + t.w, ta = t.z * t.w;

    float bi = -1.0f;
    int bp = 0;
    for (int j = 0; j < 32; ++j) {
        int p = p0 + j;
        if (p >= NP) break;
        float4 pr = ld4(prior, (size_t)p * 4);
        float px0 = pr.x - pr.z * 0.5f, py0 = pr.y - pr.w * 0.5f;
        float px1 = pr.x + pr.z * 0.5f, py1 = pr.y + pr.w * 0.5f;
        float pa = (px1 - px0) * (py1 - py0);
        float lbx = fmaxf(px0, tx0), lby = fmaxf(py0, ty0);
        float ubx = fminf(px1, tx1), uby = fminf(py1, ty1);
        float ww = fmaxf(ubx - lbx, 0.0f), hh = fmaxf(uby - lby, 0.0f);
        float inter = ww * hh;
        float iou = inter / (pa + ta - inter + 1e-6f);
        if (iou > bi) { bi = iou; bp = p; }
    }
    if (bi >= 0.0f) {
        unsigned long long packed =
            (((unsigned long long)__float_as_uint(bi)) << 32) | (~(unsigned)bp);
        atomicMax(&bestPrior[b * NO + o], packed);
    }
}

__global__ __launch_bounds__(256) void match_kernel(
        const void* __restrict__ prior, const void* __restrict__ tb,
        unsigned long long* __restrict__ bestPrior, const int* __restrict__ flag) {
    if (*flag)
        match_body<float>((const float*)prior, (const float*)tb, bestPrior);
    else
        match_body<unsigned short>((const unsigned short*)prior,
                                   (const unsigned short*)tb, bestPrior);
}

// CE load cluster for iteration i: 4 streams x 5 coalesced dwords + lane-0
// extras (x[80], x[labv]; labv==0 fetches x[0] = bit-identical fallback).
template <typename T>
__device__ __forceinline__ void ce_load(
        const T* __restrict__ pcls, const unsigned char* s_lab8,
        int i, int g, int q, int rbase,
        float (&v)[4][5], float (&v80)[4], float (&xl)[4]) {
    #pragma unroll
    for (int s = 0; s < 4; ++s) {
        int rl = i * 16 + g + s * 64;
        int labv = s_lab8[rl];
        const T* xr = pcls + (size_t)(rbase + rl) * NC;
        #pragma unroll
        for (int j = 0; j < 5; ++j) v[s][j] = ldT(xr, q + 16 * j);
        v80[s] = -1e30f; xl[s] = 0.f;
        if (q == 0) {
            v80[s] = ldT(xr, 80);
            xl[s] = ldT(xr, labv);
        }
    }
}

// CE compute cluster: per-stream 16-lane logsumexp via DPP, minus x[label].
__device__ __forceinline__ void ce_compute(
        const float (&v)[4][5], const float (&v80)[4], const float (&xl)[4],
        int q, float& c_sum) {
    #pragma unroll
    for (int s = 0; s < 4; ++s) {
        float mm = fmaxf(fmaxf(fmaxf(v[s][0], v[s][1]), fmaxf(v[s][2], v[s][3])),
                         fmaxf(v[s][4], v80[s]));
        DPP_RED16(mm, fmaxf)
        float ss = __expf(v[s][0] - mm) + __expf(v[s][1] - mm)
                 + __expf(v[s][2] - mm) + __expf(v[s][3] - mm)
                 + __expf(v[s][4] - mm) + __expf(v80[s] - mm);
        DPP_RED16(ss, addf)
        if (q == 0) c_sum += (mm + __logf(ss)) - xl[s];
    }
}

// Fused prep+CE. Phase 1 (prep, thread-per-row): per-row argmax (strict > =
// first occurrence) + force-match (ascending o, last wins) from LDS-staged
// per-batch metadata; label kept in LDS; accumulates l1/iou/npos in regs.
// Phase 2 (CE): 16 lanes/row, 4 streams x 4 iters, 2-deep software pipeline
// (ping-pong vA/vB; sched_barrier(0) pins each load cluster ahead of the
// following compute cluster). One combined block reduction + 4 atomics.
// Box formulas R7-verbatim; FP summation order identical to R10 (proven).
template <typename T>
__device__ void prepce_impl(
        const T* __restrict__ plocs, const T* __restrict__ prior,
        const T* __restrict__ tb, const int* __restrict__ tlab,
        const unsigned long long* __restrict__ bestPrior,
        const T* __restrict__ pcls, float* __restrict__ accum) {
    __shared__ float4 s_box[2][NO];          // x0,y0,x1,y1
    __shared__ float  s_area[2][NO];
    __shared__ int    s_lab[2][NO];
    __shared__ unsigned s_forced[2][NO];
    __shared__ unsigned char s_lab8[256];
    __shared__ float red[4][4];

    const int tid = threadIdx.x;
    const int lane = tid & 63;
    const int wv = tid >> 6;
    const int row = blockIdx.x * 256 + tid;
    const int b = row / NP;
    const int p = row - b * NP;
    const int b0 = (blockIdx.x * 256) / NP;

    if (tid < 64) {
        int bb = tid >> 5, o = tid & 31;
        int bq = b0 + bb;
        if (bq < NB) {
            float4 t = ld4(tb, ((size_t)(bq * NO + o)) * 4);
            s_box[bb][o] = make_float4(t.x, t.y, t.x + t.z, t.y + t.w);
            s_area[bb][o] = t.z * t.w;
            s_lab[bb][o] = tlab[bq * NO + o];
            s_forced[bb][o] = ~(unsigned)(bestPrior[bq * NO + o] & 0xffffffffull);
        }
    }
    __syncthreads();

    const int bb = b - b0;
    float4 pr = ld4(prior, (size_t)p * 4);
    float px0 = pr.x - pr.z * 0.5f, py0 = pr.y - pr.w * 0.5f;
    float px1 = pr.x + pr.z * 0.5f, py1 = pr.y + pr.w * 0.5f;
    float pa = (px1 - px0) * (py1 - py0);

    float bi = -1.0f;
    int bo = 0, fo = -1;
    #pragma unroll 8
    for (int o = 0; o < NO; ++o) {
        float4 t = s_box[bb][o];
        float lbx = fmaxf(px0, t.x), lby = fmaxf(py0, t.y);
        float ubx = fminf(px1, t.z), uby = fminf(py1, t.w);
        float ww = fmaxf(ubx - lbx, 0.0f), hh = fmaxf(uby - lby, 0.0f);
        float inter = ww * hh;
        float iou = inter / (pa + s_area[bb][o] - inter + 1e-6f);
        if (iou > bi) { bi = iou; bo = o; }
        if (s_forced[bb][o] == (unsigned)p) fo = o;
    }
    if (fo >= 0) { bo = fo; bi = 1.0f; }

    int lab = s_lab[bb][bo];
    if (bi < 0.5f) lab = 0;
    s_lab8[tid] = (unsigned char)lab;

    float l1_sum = 0.f, iou_sum = 0.f, np_sum = 0.f;
    if (lab != 0) {
        np_sum = 1.0f;
        float4 t = s_box[bb][bo];
        float x0 = t.x, y0 = t.y, x1 = t.z, y1 = t.w;
        // R7 used raw w,h for the l1 terms: reconstruct from staged xyxy is
        // NOT identical; reload raw tb box (L1-hot) to keep bit-proven math.
        float4 traw = ld4(tb, ((size_t)(b * NO + bo)) * 4);
        float tcx = (x0 + x1) * 0.5f, tcy = (y0 + y1) * 0.5f;
        float4 qv = ld4(plocs, (size_t)row * 4);
        l1_sum = fabsf(qv.x - tcx) + fabsf(qv.y - tcy)
               + fabsf(qv.z - traw.z) + fabsf(qv.w - traw.w);
        float qX0 = qv.x - qv.z * 0.5f, qY0 = qv.y - qv.w * 0.5f;
        float qX1 = qv.x + qv.z * 0.5f, qY1 = qv.y + qv.w * 0.5f;
        float lbx = fmaxf(x0, qX0), lby = fmaxf(y0, qY0);
        float ubx = fminf(x1, qX1), uby = fminf(y1, qY1);
        float iw = fmaxf(ubx - lbx, 0.f), ih = fmaxf(uby - lby, 0.f);
        float inter = iw * ih;
        float areaq = (qX1 - qX0) * (qY1 - qY0);
        float areat = (x1 - x0) * (y1 - y0);
        iou_sum = 1.0f - inter / (areat + areaq - inter + 1e-6f);
    }

    __syncthreads();   // s_lab8 complete for the whole block

    // ---- CE phase over this block's 256 rows (2-deep pipelined) ----
    const int q = lane & 15;
    const int g = wv * 4 + (lane >> 4);      // 16-lane-group id, 0..15
    const int rbase = blockIdx.x * 256;
    float c_sum = 0.f;

    float vA[4][5], vB[4][5];
    float v80A[4], v80B[4], xlA[4], xlB[4];

    ce_load(pcls, s_lab8, 0, g, q, rbase, vA, v80A, xlA);
    ce_load(pcls, s_lab8, 1, g, q, rbase, vB, v80B, xlB);
    __builtin_amdgcn_sched_barrier(0);
    ce_compute(vA, v80A, xlA, q, c_sum);
    ce_load(pcls, s_lab8, 2, g, q, rbase, vA, v80A, xlA);
    __builtin_amdgcn_sched_barrier(0);
    ce_compute(vB, v80B, xlB, q, c_sum);
    ce_load(pcls, s_lab8, 3, g, q, rbase, vB, v80B, xlB);
    __builtin_amdgcn_sched_barrier(0);
    ce_compute(vA, v80A, xlA, q, c_sum);
    ce_compute(vB, v80B, xlB, q, c_sum);

    // ---- combined block reduction: cross, l1, iou, npos ----
    #pragma unroll
    for (int d = 1; d < 64; d <<= 1) {
        c_sum   += __shfl_xor(c_sum, d);
        l1_sum  += __shfl_xor(l1_sum, d);
        iou_sum += __shfl_xor(iou_sum, d);
        np_sum  += __shfl_xor(np_sum, d);
    }
    if (lane == 0) {
        red[wv][0] = c_sum; red[wv][1] = l1_sum;
        red[wv][2] = iou_sum; red[wv][3] = np_sum;
    }
    __syncthreads();
    if (tid == 0) {
        float a0 = 0, a1 = 0, a2 = 0, a3 = 0;
        for (int k = 0; k < 4; ++k) {
            a0 += red[k][0]; a1 += red[k][1]; a2 += red[k][2]; a3 += red[k][3];
        }
        atomicAdd(&accum[0], a0);
        atomicAdd(&accum[1], a1);
        atomicAdd(&accum[2], a2);
        atomicAdd(&accum[3], a3);
    }
}

__global__ __launch_bounds__(256) void prepce_kernel(
        const void* __restrict__ plocs, const void* __restrict__ prior,
        const void* __restrict__ tb, const int* __restrict__ tlab,
        const unsigned long long* __restrict__ bestPrior,
        const void* __restrict__ pcls,
        const int* __restrict__ flag, float* __restrict__ accum) {
    if (*flag)
        prepce_impl<float>((const float*)plocs, (const float*)prior,
                           (const float*)tb, tlab, bestPrior,
                           (const float*)pcls, accum);
    else
        prepce_impl<unsigned short>((const unsigned short*)plocs,
                                    (const unsigned short*)prior,
                                    (const unsigned short*)tb,
                                    tlab, bestPrior,
                                    (const unsigned short*)pcls, accum);
}

__global__ void finalize_kernel(const float* __restrict__ accum,
                                const int* __restrict__ flag, void* __restrict__ out) {
    if (threadIdx.x == 0) {
        float cross = accum[0] / (float)NROWS;
        float npos = accum[3];
        float loc = accum[1] / (npos * 4.0f);
        float iou = accum[2] / npos;
        if (*flag) {
            float* o = (float*)out;
            o[0] = loc; o[1] = cross; o[2] = iou;
        } else {
            __hip_bfloat16* o = (__hip_bfloat16*)out;
            o[0] = __float2bfloat16(loc);
            o[1] = __float2bfloat16(cross);
            o[2] = __float2bfloat16(iou);
        }
    }
}

extern "C" void kernel_launch(void* const* d_in, const int* in_sizes, int n_in,
                              void* d_out, int out_size, void* d_ws, size_t ws_size,
                              hipStream_t stream) {
    const void* plocs = d_in[0];            // [B,P,4]
    const void* pcls  = d_in[1];            // [B,P,C]
    const void* prior = d_in[2];            // [P,4]
    const void* tb    = d_in[3];            // [B,O,4]
    const int*  tlab  = (const int*)d_in[4];// [B,O]

    char* w = (char*)d_ws;
    unsigned long long* bestPrior = (unsigned long long*)w;      // 16384 B
    float* accum = (float*)(w + 16384);                          // 16 B
    int*   flag  = (int*)(w + 16400);                            // 4 B

    hipLaunchKernelGGL(init_kernel, dim3(1), dim3(256), 0, stream,
                       prior, bestPrior, accum, flag);

    dim3 gA((NP + 255) / 256, NB);
    hipLaunchKernelGGL(match_kernel, gA, dim3(256), 0, stream,
                       prior, tb, bestPrior, flag);

    hipLaunchKernelGGL(prepce_kernel, dim3(PBLK), dim3(256), 0, stream,
                       plocs, prior, tb, tlab, bestPrior, pcls, flag, accum);

    hipLaunchKernelGGL(finalize_kernel, dim3(1), dim3(64), 0, stream,
                       accum, flag, d_out);
}

// Round 7
// 358.734 us; speedup vs baseline: 1.0131x; 1.0131x over previous
//
#include <hip/hip_runtime.h>
#include <hip/hip_bf16.h>

#define NB 64
#define NP 8732
#define NO 32
#define NC 81
#define NROWS (NB * NP)          // 558848 = 2183*256
#define PBLK 2183

// ws layout: [0,16384)      u64 bestPrior[NB*NO] packed (iou_bits<<32)|~p
//            [16384,16400)  float accum[4] {cross, l1, iou, npos}
//            [16400,16404)  int flag (1 = f32 inputs, 0 = bf16)
// HISTORY: inputs are FLOAT32 at runtime (flag=1 is the passing path); the
// runtime-dtype flag is load-bearing — do not hard-code a dtype.
// R9: prep+ce fused (block owns 256 rows; labels via LDS).
// R10: DPP row_ror reductions; 4 row-streams. 149->144.5 only; VGPR=28.
// R13: ping-pong + sched_barrier pipeline; VGPR 52 BUT launch_bounds(256,2)
//      capped occupancy at 29.5% -> 138 us. (2nd arg = waves/EU cap on hipcc!)
// R14: uncapped; no change (VGPR still 52 => pipeline never materialized:
//      ping-pong needs >=56 live floats; the if(q==0) exec-branches inside
//      ce_load fragment scheduler regions -> loads re-serialized per use).
// R15: BRANCH-FREE load clusters: labels pre-read to regs; v80/xl loaded
//      unmasked (broadcast addr) and re-masked in compute via cndmask.
//      Bit-identical accumulation (exp(-1e30-m)=0; only q==0 accumulates).

__device__ __forceinline__ float ldT(const float* p, size_t i) { return p[i]; }
__device__ __forceinline__ float ldT(const unsigned short* p, size_t i) {
    return __uint_as_float((unsigned)p[i] << 16);
}
__device__ __forceinline__ float4 ld4(const float* p, size_t i) {
    return *(const float4*)(p + i);
}
__device__ __forceinline__ float4 ld4(const unsigned short* p, size_t i) {
    ushort4 u = *(const ushort4*)(p + i);
    return make_float4(__uint_as_float((unsigned)u.x << 16),
                       __uint_as_float((unsigned)u.y << 16),
                       __uint_as_float((unsigned)u.z << 16),
                       __uint_as_float((unsigned)u.w << 16));
}

// DPP row_ror:N within each 16-lane row — VALU-pipe cross-lane, no LDS.
template <int CTRL>
__device__ __forceinline__ float dppf(float x) {
    return __int_as_float(__builtin_amdgcn_update_dpp(
        0, __float_as_int(x), CTRL, 0xF, 0xF, true));
}
// full 16-lane reduce: ror 8,4,2,1 (all lanes end with the total)
#define DPP_RED16(var, OP)                      \
    var = OP(var, dppf<0x128>(var));            \
    var = OP(var, dppf<0x124>(var));            \
    var = OP(var, dppf<0x122>(var));            \
    var = OP(var, dppf<0x121>(var));
__device__ __forceinline__ float addf(float a, float b) { return a + b; }

__global__ void init_kernel(const void* __restrict__ prior,
                            unsigned long long* __restrict__ bestPrior,
                            float* __restrict__ accum, int* __restrict__ flag) {
    int i = threadIdx.x;
    for (int j = i; j < NB * NO; j += blockDim.x) bestPrior[j] = 0ull;
    if (i < 4) accum[i] = 0.0f;
    if (i < 64) {
        const unsigned short* pb = (const unsigned short*)prior;
        float v = __uint_as_float((unsigned)pb[i] << 16);
        unsigned long long bad = __ballot(!(fabsf(v) <= 8.0f));
        if (i == 0) *flag = (__popcll(bad) >= 8) ? 1 : 0;
    }
}

// Per-(b,o) argmax over priors (R7/R8-proven): strict > keeps first max;
// packed u64 atomicMax merges (larger iou wins; ties -> smaller p via ~p).
template <typename T>
__device__ __forceinline__ void match_body(
        const T* __restrict__ prior, const T* __restrict__ tb,
        unsigned long long* __restrict__ bestPrior) {
    const int b   = blockIdx.y;
    const int o   = threadIdx.x & 31;
    const int seg = threadIdx.x >> 5;
    const int p0  = blockIdx.x * 256 + seg * 32;

    float4 t = ld4(tb, ((size_t)(b * NO + o)) * 4);
    float tx0 = t.x, ty0 = t.y, tx1 = t.x + t.z, ty1 = t.y + t.w, ta = t.z * t.w;

    float bi = -1.0f;
    int bp = 0;
    for (int j = 0; j < 32; ++j) {
        int p = p0 + j;
        if (p >= NP) break;
        float4 pr = ld4(prior, (size_t)p * 4);
        float px0 = pr.x - pr.z * 0.5f, py0 = pr.y - pr.w * 0.5f;
        float px1 = pr.x + pr.z * 0.5f, py1 = pr.y + pr.w * 0.5f;
        float pa = (px1 - px0) * (py1 - py0);
        float lbx = fmaxf(px0, tx0), lby = fmaxf(py0, ty0);
        float ubx = fminf(px1, tx1), uby = fminf(py1, ty1);
        float ww = fmaxf(ubx - lbx, 0.0f), hh = fmaxf(uby - lby, 0.0f);
        float inter = ww * hh;
        float iou = inter / (pa + ta - inter + 1e-6f);
        if (iou > bi) { bi = iou; bp = p; }
    }
    if (bi >= 0.0f) {
        unsigned long long packed =
            (((unsigned long long)__float_as_uint(bi)) << 32) | (~(unsigned)bp);
        atomicMax(&bestPrior[b * NO + o], packed);
    }
}

__global__ __launch_bounds__(256) void match_kernel(
        const void* __restrict__ prior, const void* __restrict__ tb,
        unsigned long long* __restrict__ bestPrior, const int* __restrict__ flag) {
    if (*flag)
        match_body<float>((const float*)prior, (const float*)tb, bestPrior);
    else
        match_body<unsigned short>((const unsigned short*)prior,
                                   (const unsigned short*)tb, bestPrior);
}

// CE load cluster for iteration i — BRANCH-FREE (no exec-mask toggles):
// 4 streams x (5 coalesced dwords + x[80] + x[labv], both broadcast loads).
template <typename T>
__device__ __forceinline__ void ce_load_u(
        const T* __restrict__ pcls, int i, int g, int q, int rbase,
        const int (&labv)[4],
        float (&v)[4][5], float (&v80)[4], float (&xl)[4]) {
    #pragma unroll
    for (int s = 0; s < 4; ++s) {
        int rl = i * 16 + g + s * 64;
        const T* xr = pcls + (size_t)(rbase + rl) * NC;
        #pragma unroll
        for (int j = 0; j < 5; ++j) v[s][j] = ldT(xr, q + 16 * j);
        v80[s] = ldT(xr, 80);        // all lanes, same addr per row: broadcast
        xl[s]  = ldT(xr, labv[s]);   // all lanes, same addr per row: broadcast
    }
}

// CE compute cluster: per-stream 16-lane logsumexp via DPP, minus x[label].
// Branchless masking: e80 select reproduces the q==0-only -1e30 sentinel;
// c_sum select reproduces q==0-only accumulation. Bit-identical to R13.
__device__ __forceinline__ void ce_compute_u(
        const float (&v)[4][5], const float (&v80)[4], const float (&xl)[4],
        int q, float& c_sum) {
    #pragma unroll
    for (int s = 0; s < 4; ++s) {
        float e80 = (q == 0) ? v80[s] : -1e30f;
        float mm = fmaxf(fmaxf(fmaxf(v[s][0], v[s][1]), fmaxf(v[s][2], v[s][3])),
                         fmaxf(v[s][4], e80));
        DPP_RED16(mm, fmaxf)
        float ss = __expf(v[s][0] - mm) + __expf(v[s][1] - mm)
                 + __expf(v[s][2] - mm) + __expf(v[s][3] - mm)
                 + __expf(v[s][4] - mm) + __expf(e80 - mm);
        DPP_RED16(ss, addf)
        float term = (mm + __logf(ss)) - xl[s];
        c_sum += (q == 0) ? term : 0.0f;
    }
}

// Fused prep+CE. Phase 1 (prep, thread-per-row): per-row argmax (strict > =
// first occurrence) + force-match (ascending o, last wins) from LDS-staged
// per-batch metadata; label kept in LDS; accumulates l1/iou/npos in regs.
// Phase 2 (CE): 16 lanes/row, 4 streams x 4 iters, 2-deep software pipeline;
// load clusters are branch-free single scheduler regions pinned by
// sched_barrier(0). One combined block reduction + 4 atomics.
template <typename T>
__device__ void prepce_impl(
        const T* __restrict__ plocs, const T* __restrict__ prior,
        const T* __restrict__ tb, const int* __restrict__ tlab,
        const unsigned long long* __restrict__ bestPrior,
        const T* __restrict__ pcls, float* __restrict__ accum) {
    __shared__ float4 s_box[2][NO];          // x0,y0,x1,y1
    __shared__ float  s_area[2][NO];
    __shared__ int    s_lab[2][NO];
    __shared__ unsigned s_forced[2][NO];
    __shared__ unsigned char s_lab8[256];
    __shared__ float red[4][4];

    const int tid = threadIdx.x;
    const int lane = tid & 63;
    const int wv = tid >> 6;
    const int row = blockIdx.x * 256 + tid;
    const int b = row / NP;
    const int p = row - b * NP;
    const int b0 = (blockIdx.x * 256) / NP;

    if (tid < 64) {
        int bb = tid >> 5, o = tid & 31;
        int bq = b0 + bb;
        if (bq < NB) {
            float4 t = ld4(tb, ((size_t)(bq * NO + o)) * 4);
            s_box[bb][o] = make_float4(t.x, t.y, t.x + t.z, t.y + t.w);
            s_area[bb][o] = t.z * t.w;
            s_lab[bb][o] = tlab[bq * NO + o];
            s_forced[bb][o] = ~(unsigned)(bestPrior[bq * NO + o] & 0xffffffffull);
        }
    }
    __syncthreads();

    const int bb = b - b0;
    float4 pr = ld4(prior, (size_t)p * 4);
    float px0 = pr.x - pr.z * 0.5f, py0 = pr.y - pr.w * 0.5f;
    float px1 = pr.x + pr.z * 0.5f, py1 = pr.y + pr.w * 0.5f;
    float pa = (px1 - px0) * (py1 - py0);

    float bi = -1.0f;
    int bo = 0, fo = -1;
    #pragma unroll 8
    for (int o = 0; o < NO; ++o) {
        float4 t = s_box[bb][o];
        float lbx = fmaxf(px0, t.x), lby = fmaxf(py0, t.y);
        float ubx = fminf(px1, t.z), uby = fminf(py1, t.w);
        float ww = fmaxf(ubx - lbx, 0.0f), hh = fmaxf(uby - lby, 0.0f);
        float inter = ww * hh;
        float iou = inter / (pa + s_area[bb][o] - inter + 1e-6f);
        if (iou > bi) { bi = iou; bo = o; }
        if (s_forced[bb][o] == (unsigned)p) fo = o;
    }
    if (fo >= 0) { bo = fo; bi = 1.0f; }

    int lab = s_lab[bb][bo];
    if (bi < 0.5f) lab = 0;
    s_lab8[tid] = (unsigned char)lab;

    float l1_sum = 0.f, iou_sum = 0.f, np_sum = 0.f;
    if (lab != 0) {
        np_sum = 1.0f;
        float4 t = s_box[bb][bo];
        float x0 = t.x, y0 = t.y, x1 = t.z, y1 = t.w;
        // R7 used raw w,h for the l1 terms: reconstruct from staged xyxy is
        // NOT identical; reload raw tb box (L1-hot) to keep bit-proven math.
        float4 traw = ld4(tb, ((size_t)(b * NO + bo)) * 4);
        float tcx = (x0 + x1) * 0.5f, tcy = (y0 + y1) * 0.5f;
        float4 qv = ld4(plocs, (size_t)row * 4);
        l1_sum = fabsf(qv.x - tcx) + fabsf(qv.y - tcy)
               + fabsf(qv.z - traw.z) + fabsf(qv.w - traw.w);
        float qX0 = qv.x - qv.z * 0.5f, qY0 = qv.y - qv.w * 0.5f;
        float qX1 = qv.x + qv.z * 0.5f, qY1 = qv.y + qv.w * 0.5f;
        float lbx = fmaxf(x0, qX0), lby = fmaxf(y0, qY0);
        float ubx = fminf(x1, qX1), uby = fminf(y1, qY1);
        float iw = fmaxf(ubx - lbx, 0.f), ih = fmaxf(uby - lby, 0.f);
        float inter = iw * ih;
        float areaq = (qX1 - qX0) * (qY1 - qY0);
        float areat = (x1 - x0) * (y1 - y0);
        iou_sum = 1.0f - inter / (areat + areaq - inter + 1e-6f);
    }

    __syncthreads();   // s_lab8 complete for the whole block

    // ---- CE phase over this block's 256 rows (2-deep pipelined) ----
    const int q = lane & 15;
    const int g = wv * 4 + (lane >> 4);      // 16-lane-group id, 0..15
    const int rbase = blockIdx.x * 256;
    float c_sum = 0.f;

    // all 16 labels into registers BEFORE the global-load phase (LDS latency
    // off the VMEM critical path; statically indexed per rule #20)
    int labv[4][4];
    #pragma unroll
    for (int i = 0; i < 4; ++i)
        #pragma unroll
        for (int s = 0; s < 4; ++s)
            labv[i][s] = s_lab8[i * 16 + g + s * 64];

    float vA[4][5], vB[4][5];
    float v80A[4], v80B[4], xlA[4], xlB[4];

    ce_load_u(pcls, 0, g, q, rbase, labv[0], vA, v80A, xlA);
    ce_load_u(pcls, 1, g, q, rbase, labv[1], vB, v80B, xlB);
    __builtin_amdgcn_sched_barrier(0);
    ce_compute_u(vA, v80A, xlA, q, c_sum);
    ce_load_u(pcls, 2, g, q, rbase, labv[2], vA, v80A, xlA);
    __builtin_amdgcn_sched_barrier(0);
    ce_compute_u(vB, v80B, xlB, q, c_sum);
    ce_load_u(pcls, 3, g, q, rbase, labv[3], vB, v80B, xlB);
    __builtin_amdgcn_sched_barrier(0);
    ce_compute_u(vA, v80A, xlA, q, c_sum);
    ce_compute_u(vB, v80B, xlB, q, c_sum);

    // ---- combined block reduction: cross, l1, iou, npos ----
    #pragma unroll
    for (int d = 1; d < 64; d <<= 1) {
        c_sum   += __shfl_xor(c_sum, d);
        l1_sum  += __shfl_xor(l1_sum, d);
        iou_sum += __shfl_xor(iou_sum, d);
        np_sum  += __shfl_xor(np_sum, d);
    }
    if (lane == 0) {
        red[wv][0] = c_sum; red[wv][1] = l1_sum;
        red[wv][2] = iou_sum; red[wv][3] = np_sum;
    }
    __syncthreads();
    if (tid == 0) {
        float a0 = 0, a1 = 0, a2 = 0, a3 = 0;
        for (int k = 0; k < 4; ++k) {
            a0 += red[k][0]; a1 += red[k][1]; a2 += red[k][2]; a3 += red[k][3];
        }
        atomicAdd(&accum[0], a0);
        atomicAdd(&accum[1], a1);
        atomicAdd(&accum[2], a2);
        atomicAdd(&accum[3], a3);
    }
}

__global__ __launch_bounds__(256) void prepce_kernel(
        const void* __restrict__ plocs, const void* __restrict__ prior,
        const void* __restrict__ tb, const int* __restrict__ tlab,
        const unsigned long long* __restrict__ bestPrior,
        const void* __restrict__ pcls,
        const int* __restrict__ flag, float* __restrict__ accum) {
    if (*flag)
        prepce_impl<float>((const float*)plocs, (const float*)prior,
                           (const float*)tb, tlab, bestPrior,
                           (const float*)pcls, accum);
    else
        prepce_impl<unsigned short>((const unsigned short*)plocs,
                                    (const unsigned short*)prior,
                                    (const unsigned short*)tb,
                                    tlab, bestPrior,
                                    (const unsigned short*)pcls, accum);
}

__global__ void finalize_kernel(const float* __restrict__ accum,
                                const int* __restrict__ flag, void* __restrict__ out) {
    if (threadIdx.x == 0) {
        float cross = accum[0] / (float)NROWS;
        float npos = accum[3];
        float loc = accum[1] / (npos * 4.0f);
        float iou = accum[2] / npos;
        if (*flag) {
            float* o = (float*)out;
            o[0] = loc; o[1] = cross; o[2] = iou;
        } else {
            __hip_bfloat16* o = (__hip_bfloat16*)out;
            o[0] = __float2bfloat16(loc);
            o[1] = __float2bfloat16(cross);
            o[2] = __float2bfloat16(iou);
        }
    }
}

extern "C" void kernel_launch(void* const* d_in, const int* in_sizes, int n_in,
                              void* d_out, int out_size, void* d_ws, size_t ws_size,
                              hipStream_t stream) {
    const void* plocs = d_in[0];            // [B,P,4]
    const void* pcls  = d_in[1];            // [B,P,C]
    const void* prior = d_in[2];            // [P,4]
    const void* tb    = d_in[3];            // [B,O,4]
    const int*  tlab  = (const int*)d_in[4];// [B,O]

    char* w = (char*)d_ws;
    unsigned long long* bestPrior = (unsigned long long*)w;      // 16384 B
    float* accum = (float*)(w + 16384);                          // 16 B
    int*   flag  = (int*)(w + 16400);                            // 4 B

    hipLaunchKernelGGL(init_kernel, dim3(1), dim3(256), 0, stream,
                       prior, bestPrior, accum, flag);

    dim3 gA((NP + 255) / 256, NB);
    hipLaunchKernelGGL(match_kernel, gA, dim3(256), 0, stream,
                       prior, tb, bestPrior, flag);

    hipLaunchKernelGGL(prepce_kernel, dim3(PBLK), dim3(256), 0, stream,
                       plocs, prior, tb, tlab, bestPrior, pcls, flag, accum);

    hipLaunchKernelGGL(finalize_kernel, dim3(1), dim3(64), 0, stream,
                       accum, flag, d_out);
}